// Round 11
// baseline (283.239 us; speedup 1.0000x reference)
//
#include <hip/hip_runtime.h>
#include <hip/hip_bf16.h>

#define B_N 2048
#define E_N 64
#define D_N 512
#define O_N 512
#define NSL 4     // k-slices
#define KS  128   // k per slice
#define WLD 66    // ws row stride in ushorts

typedef __bf16 bf16x8 __attribute__((ext_vector_type(8)));
typedef float  f32x4  __attribute__((ext_vector_type(4)));

__device__ __forceinline__ unsigned cvt2(float a, float b) {
  union { __hip_bfloat162 h; unsigned u; } c;
  c.h = __float22bfloat162_rn(make_float2(a, b));
  return c.u;
}

// ---------------- helpers (verified R7-R10) ----------------
__global__ __launch_bounds__(256)
void bucket_kernel(const int* __restrict__ opt, int* __restrict__ cnt,
                   int* __restrict__ list) {
  int b = blockIdx.x * 256 + threadIdx.x;
  int e = opt[b];
  int slot = atomicAdd(&cnt[e], 1);
  list[e * B_N + slot] = b;
}

__global__ __launch_bounds__(256)
void bias_init_kernel(const int* __restrict__ opt, const float* __restrict__ bias,
                      float* __restrict__ out) {
  int gid = blockIdx.x * 256 + threadIdx.x;
  int b  = gid >> 7;
  int o4 = gid & 127;
  int e  = opt[b];
  reinterpret_cast<float4*>(out)[(size_t)b * 128 + o4] =
      reinterpret_cast<const float4*>(bias)[(size_t)e * 128 + o4];
}

// ---------------- PROBES (diagnostic; write only to d_ws) ----------------
// P1: read all 64 MB of W, perfectly sequential (1 KB per wave-instr),
// 8 independent float4 in flight per thread (sched_barrier pins the split).
__global__ __launch_bounds__(256)
void probe_seq(const float* __restrict__ w, float* __restrict__ acc) {
  const size_t g0 = (size_t)blockIdx.x * 256 + threadIdx.x;   // 2048 blocks
  const float4* p = reinterpret_cast<const float4*>(w);
  float4 v[8];
#pragma unroll
  for (int i = 0; i < 8; ++i) v[i] = p[(size_t)i * 524288 + g0];
  __builtin_amdgcn_sched_barrier(0);
  float s = 0.f;
#pragma unroll
  for (int i = 0; i < 8; ++i) s += v[i].x + v[i].y + v[i].z + v[i].w;
#pragma unroll
  for (int o = 32; o; o >>= 1) s += __shfl_down(s, o);
  if ((threadIdx.x & 63) == 0) atomicAdd(acc, s);
}

// P2: same 64 MB, same MLP, but in R10's granule pattern:
// 256 B row-chunks at 2 KB stride (64-col tile of a 512-col matrix).
__global__ __launch_bounds__(256)
void probe_strided(const float* __restrict__ w, float* __restrict__ acc) {
  const int e = blockIdx.x & 63;
  const int s = (blockIdx.x >> 6) & 3;
  const int q = blockIdx.x >> 8;
  const float* wsl = w + (size_t)e * 262144 + s * 65536 + q * 64;
  float4 v[8];
#pragma unroll
  for (int i = 0; i < 8; ++i) {
    int idx = threadIdx.x + i * 256;
    int row = idx >> 4;
    int c4  = idx & 15;
    v[i] = *reinterpret_cast<const float4*>(wsl + (size_t)row * O_N + c4 * 4);
  }
  __builtin_amdgcn_sched_barrier(0);
  float sm = 0.f;
#pragma unroll
  for (int i = 0; i < 8; ++i) sm += v[i].x + v[i].y + v[i].z + v[i].w;
#pragma unroll
  for (int o = 32; o; o >>= 1) sm += __shfl_down(sm, o);
  if ((threadIdx.x & 63) == 0) atomicAdd(acc, sm);
}

// P3: R10's compute phase without W staging / out-atomics:
// cnt+list loads, scattered x-gather, cvt, MFMA chain (A used as both operands).
__global__ __launch_bounds__(256, 6)
void probe_compute(const float* __restrict__ x, const int* __restrict__ cnt,
                   const int* __restrict__ list, float* __restrict__ acc) {
  const int e    = blockIdx.x;
  const int s    = blockIdx.y;
  const int t    = threadIdx.x;
  const int lane = t & 63;
  const int n    = cnt[e];
  if (n == 0) return;
  const int m_in = lane & 15;
  const int g    = lane >> 4;
  const int* mylist = list + e * B_N;
  const float* xsl = x + (size_t)s * KS;

  f32x4 accv = {0.f, 0.f, 0.f, 0.f};
  for (int m0 = 0; m0 < n; m0 += 16) {
    int sa = m0 + m_in;
    const float* xr = xsl + (size_t)mylist[sa < n ? sa : 0] * D_N + g * 8;
#pragma unroll
    for (int ks = 0; ks < 4; ++ks) {
      union { float4 q2[2]; float e8[8]; } xa;
      xa.q2[0] = *reinterpret_cast<const float4*>(xr + ks * 32);
      xa.q2[1] = *reinterpret_cast<const float4*>(xr + ks * 32 + 4);
      union { unsigned u[4]; bf16x8 v; } a;
#pragma unroll
      for (int p = 0; p < 4; ++p) a.u[p] = cvt2(xa.e8[2 * p], xa.e8[2 * p + 1]);
      accv = __builtin_amdgcn_mfma_f32_16x16x32_bf16(a.v, a.v, accv, 0, 0, 0);
    }
  }
  float sm = accv[0] + accv[1] + accv[2] + accv[3];
#pragma unroll
  for (int o = 32; o; o >>= 1) sm += __shfl_down(sm, o);
  if ((threadIdx.x & 63) == 0) atomicAdd(acc, sm);
}

// ---------------- R10 gemm, verbatim (passed @ 44 us) ----------------
__global__ __launch_bounds__(256, 6)
void gemm_kernel(const float* __restrict__ x, const float* __restrict__ w,
                 const int* __restrict__ cnt, const int* __restrict__ list,
                 float* __restrict__ out) {
  __shared__ unsigned short ws[KS * WLD];

  const int e    = blockIdx.x;
  const int s    = blockIdx.y;
  const int q    = blockIdx.z;
  const int t    = threadIdx.x;
  const int lane = t & 63;
  const int wave = t >> 6;
  const int n    = cnt[e];
  if (n == 0) return;

  const int m_in = lane & 15;
  const int g    = lane >> 4;
  const int* mylist = list + e * B_N;

  const float* wsl = w + (size_t)e * D_N * O_N + (size_t)s * KS * O_N + q * 64;
#pragma unroll
  for (int rnd = 0; rnd < 2; ++rnd) {
    float4 f[4];
#pragma unroll
    for (int i = 0; i < 4; ++i) {
      int idx = t + (rnd * 4 + i) * 256;
      int row = idx >> 4;
      int c4  = idx & 15;
      f[i] = *reinterpret_cast<const float4*>(wsl + (size_t)row * O_N + c4 * 4);
    }
#pragma unroll
    for (int i = 0; i < 4; ++i) {
      int idx = t + (rnd * 4 + i) * 256;
      int row = idx >> 4;
      int c4  = idx & 15;
      *reinterpret_cast<uint2*>(&ws[row * WLD + c4 * 4]) =
          make_uint2(cvt2(f[i].x, f[i].y), cvt2(f[i].z, f[i].w));
    }
  }
  __syncthreads();

  union { unsigned short us[8]; bf16x8 v; } frag[4];
#pragma unroll
  for (int ks = 0; ks < 4; ++ks)
#pragma unroll
    for (int j = 0; j < 8; ++j)
      frag[ks].us[j] = ws[(ks * 32 + g * 8 + j) * WLD + wave * 16 + m_in];

  const float* xsl = x + (size_t)s * KS;
  const int ocol = q * 64 + wave * 16 + m_in;

  for (int m0 = 0; m0 < n; m0 += 16) {
    int sa = m0 + m_in;
    const float* xr = xsl + (size_t)mylist[sa < n ? sa : 0] * D_N + g * 8;

    f32x4 acc = {0.f, 0.f, 0.f, 0.f};
#pragma unroll
    for (int ks = 0; ks < 4; ++ks) {
      union { float4 q2[2]; float e8[8]; } xa;
      xa.q2[0] = *reinterpret_cast<const float4*>(xr + ks * 32);
      xa.q2[1] = *reinterpret_cast<const float4*>(xr + ks * 32 + 4);
      union { unsigned u[4]; bf16x8 v; } a;
#pragma unroll
      for (int p = 0; p < 4; ++p) a.u[p] = cvt2(xa.e8[2 * p], xa.e8[2 * p + 1]);
      acc = __builtin_amdgcn_mfma_f32_16x16x32_bf16(a.v, frag[ks].v, acc, 0, 0, 0);
    }

#pragma unroll
    for (int r = 0; r < 4; ++r) {
      int so = m0 + g * 4 + r;
      if (so < n)
        atomicAdd(out + (size_t)mylist[so] * O_N + ocol, acc[r]);
    }
  }
}

extern "C" void kernel_launch(void* const* d_in, const int* in_sizes, int n_in,
                              void* d_out, int out_size, void* d_ws, size_t ws_size,
                              hipStream_t stream) {
  const float* x      = (const float*)d_in[0];
  const int*   option = (const int*)d_in[1];
  const float* weight = (const float*)d_in[2];
  const float* bias   = (const float*)d_in[3];
  float* out = (float*)d_out;

  int*   cnt  = (int*)d_ws;                       // [0,256): counters
  float* pacc = (float*)((char*)d_ws + 256);      // [256,512): probe sinks
  int*   list = (int*)((char*)d_ws + 512);        // [512, +512K)

  hipMemsetAsync(cnt, 0, E_N * sizeof(int), stream);
  bucket_kernel<<<B_N / 256, 256, 0, stream>>>(option, cnt, list);
  bias_init_kernel<<<(B_N * O_N / 4) / 256, 256, 0, stream>>>(option, bias, out);

  probe_seq<<<2048, 256, 0, stream>>>(weight, pacc);
  probe_strided<<<2048, 256, 0, stream>>>(weight, pacc + 1);

  gemm_kernel<<<dim3(E_N, NSL, 8), 256, 0, stream>>>(x, weight, cnt, list, out);

  probe_compute<<<dim3(E_N, NSL), 256, 0, stream>>>(x, cnt, list, pacc + 2);
}